// Round 1
// baseline (233.141 us; speedup 1.0000x reference)
//
#include <hip/hip_runtime.h>
#include <stdint.h>

#define N_PP   8192
#define DIM    16
#define NEDGE  262144
#define LOG2E  1.4426950408889634f

// Fused grid: [0,256) edge blocks; [256, 256+1024) ap matrix quanta;
// then 544 pp quanta. Matrix quantum = (128-col group g, 512-row chunk c).
// Each wave owns one 32-col strip; 16 row-tiles of 32 rows per chunk.
#define NB_EDGE 256
#define NQ_AP   1024
#define NQ_PP   544
#define NB_TOT  (NB_EDGE + NQ_AP + NQ_PP)   // 1824

// ws float-unit layout: [0]=nonlink_pp [1]=link_pp [2]=nonlink_ap
// [3]=link_ap [4]=completion counter (uint). Zeroed by hipMemsetAsync.

typedef short    bf16x8 __attribute__((ext_vector_type(8)));
typedef float    f32x4  __attribute__((ext_vector_type(4)));
typedef float    f32x16 __attribute__((ext_vector_type(16)));
typedef unsigned u32x4  __attribute__((ext_vector_type(4)));

__device__ __forceinline__ float waveReduce(float v) {
#pragma unroll
    for (int off = 32; off > 0; off >>= 1)
        v += __shfl_down(v, off, 64);
    return v;
}

__device__ __forceinline__ unsigned bf16_rne(float f) {
    unsigned u = __builtin_bit_cast(unsigned, f);
    return (u + 0x7FFFu + ((u >> 16) & 1u)) >> 16;
}
__device__ __forceinline__ unsigned packbf2(float a, float b) {
    return bf16_rne(a) | (bf16_rne(b) << 16);
}

__global__ __launch_bounds__(256) void fused_kernel(
    const float* __restrict__ p_star, const float* __restrict__ p,
    const float* __restrict__ a, const float* __restrict__ beta_ap,
    const float* __restrict__ gamma_pp, const int* __restrict__ edges_pp,
    const int* __restrict__ edges_ap, float* __restrict__ ws,
    float* __restrict__ out)
{
    // sbuf: [0,4096) u32: A-chunk, 512 rows x 32B bf16 (row-linear)
    //       [4096,5120) u32: 512 x (|x|^2, rowbias*LOG2E) float pairs
    __shared__ uint32_t sbuf[5120];
    __shared__ float smred[4];
    const int b = blockIdx.x, tid = threadIdx.x;
    const int wid = tid >> 6, lane = tid & 63;

    if (b < NB_EDGE) {
        // ---------------- edge (link-term) blocks ----------------
        const bool isPPe = (b < 128);
        const int  base  = (isPPe ? b : b - 128) * 2048;
        float sum = 0.f;
#pragma unroll
        for (int k = 0; k < 8; ++k) {
            const int e = base + k * 256 + tid;
            const float* yrow; float bias; int e0;
            if (isPPe) {
                e0 = edges_pp[e];
                const int e1 = edges_pp[NEDGE + e];
                yrow = p + e1 * DIM;
                bias = gamma_pp[e0] + gamma_pp[N_PP + e1];
            } else {
                e0 = edges_ap[e];
                const int e1 = edges_ap[NEDGE + e];
                yrow = a + (e1 - N_PP) * DIM;
                bias = beta_ap[e0] + beta_ap[e1];
            }
            const float4* xp4 = (const float4*)(p_star + e0 * DIM);
            const float4* yp4 = (const float4*)yrow;
            float d2 = 0.f;
#pragma unroll
            for (int kk = 0; kk < 4; ++kk) {
                const float4 xv = xp4[kk], yv = yp4[kk];
                const float dx = xv.x - yv.x, dy = xv.y - yv.y,
                            dz = xv.z - yv.z, dw = xv.w - yv.w;
                d2 += dx*dx + dy*dy + dz*dz + dw*dw;
            }
            sum += bias - __builtin_amdgcn_sqrtf(d2);
        }
        const float wsum = waveReduce(sum);
        if ((tid & 63) == 0) smred[wid] = wsum;
        __syncthreads();
        if (tid == 0)
            atomicAdd(&ws[isPPe ? 1 : 3],
                      smred[0] + smred[1] + smred[2] + smred[3]);
    } else {
        // ---------------- matrix (nonlink-term) blocks ----------------
        const int  b2   = b - NB_EDGE;
        const bool isPP = (b2 >= NQ_AP);
        int g, c;
        if (!isPP) { g = b2 >> 4; c = b2 & 15; }
        else {
            const int qq = b2 - NQ_AP;
            int bnd = 0;
            while (2 * (bnd + 1) * (bnd + 2) <= qq) ++bnd;  // band of 4 groups
            const int r = qq - 2 * bnd * (bnd + 1);
            g = 4 * bnd + r / (bnd + 1);
            c = r % (bnd + 1);
        }
        const int R0 = c << 9;                    // chunk row base
        const int lane31 = lane & 31, kh = lane >> 5;

        const float* Ysrc = isPP ? p : a;
        const float* rB   = isPP ? gamma_pp : beta_ap;          // row bias
        const float* cBi  = (isPP ? gamma_pp : beta_ap) + N_PP; // col bias

        // stage A rows: thread t handles rows t and t+256 (2-way LDS, free)
        for (int rr = tid; rr < 512; rr += 256) {
            const float4* rp = (const float4*)(p_star + (R0 + rr) * DIM);
            const float4 f0 = rp[0], f1 = rp[1], f2 = rp[2], f3 = rp[3];
            const float n2 =
                f0.x*f0.x + f0.y*f0.y + f0.z*f0.z + f0.w*f0.w +
                f1.x*f1.x + f1.y*f1.y + f1.z*f1.z + f1.w*f1.w +
                f2.x*f2.x + f2.y*f2.y + f2.z*f2.z + f2.w*f2.w +
                f3.x*f3.x + f3.y*f3.y + f3.z*f3.z + f3.w*f3.w;
            const u32x4 u0 = { packbf2(f0.x,f0.y), packbf2(f0.z,f0.w),
                               packbf2(f1.x,f1.y), packbf2(f1.z,f1.w) };
            const u32x4 u1 = { packbf2(f2.x,f2.y), packbf2(f2.z,f2.w),
                               packbf2(f3.x,f3.y), packbf2(f3.z,f3.w) };
            *(u32x4*)&sbuf[rr * 8]     = u0;
            *(u32x4*)&sbuf[rr * 8 + 4] = u1;
            float2 xb;
            xb.x = n2;
            xb.y = rB[R0 + rr] * LOG2E;
            *(float2*)((float*)sbuf + 4096 + rr * 2) = xb;
        }

        // per-wave 32-col strip: B frag (col=lane%32, k-half=lane/32)
        const int s = (g << 2) + wid;
        const int j = (s << 5) + lane31;
        const float4* yp4 = (const float4*)(Ysrc + j * DIM);
        const float4 yv0 = yp4[0], yv1 = yp4[1], yv2 = yp4[2], yv3 = yp4[3];
        const float y2c =
            yv0.x*yv0.x + yv0.y*yv0.y + yv0.z*yv0.z + yv0.w*yv0.w +
            yv1.x*yv1.x + yv1.y*yv1.y + yv1.z*yv1.z + yv1.w*yv1.w +
            yv2.x*yv2.x + yv2.y*yv2.y + yv2.z*yv2.z + yv2.w*yv2.w +
            yv3.x*yv3.x + yv3.y*yv3.y + yv3.z*yv3.z + yv3.w*yv3.w;
        const float4 ha = kh ? yv2 : yv0, hb = kh ? yv3 : yv1;
        const u32x4 bupk = { packbf2(ha.x,ha.y), packbf2(ha.z,ha.w),
                             packbf2(hb.x,hb.y), packbf2(hb.z,hb.w) };
        const bf16x8 bfrag = __builtin_bit_cast(bf16x8, bupk);
        const float Ec = __expf(cBi[j]);

        __syncthreads();

        const int sl    = s - (c << 4);           // local diagonal tile idx
        const int tlEnd = isPP ? (sl < 15 ? sl : 15) : 15;
        const int dTl   = isPP ? sl : -1;
        const int aoff  = (lane31 << 3) + (kh << 2);
        const float* xbb = (const float*)sbuf + 4096 + (kh << 3);
        const int kh4 = kh << 2;

        const f32x16 zero16 = {0.f,0.f,0.f,0.f,0.f,0.f,0.f,0.f,
                               0.f,0.f,0.f,0.f,0.f,0.f,0.f,0.f};
        float acc0 = 0.f, acc1 = 0.f, acc2 = 0.f, acc3 = 0.f;

        u32x4 a_cur = *(const u32x4*)&sbuf[aoff];
        for (int tl = 0; tl <= tlEnd; ++tl) {
            const f32x16 dm = __builtin_amdgcn_mfma_f32_32x32x16_bf16(
                __builtin_bit_cast(bf16x8, a_cur), bfrag, zero16, 0, 0, 0);
            if (tl < tlEnd)                         // prefetch next A frag
                a_cur = *(const u32x4*)&sbuf[((tl + 1) << 8) + aoff];
            // (x2,bias) pairs for the 16 rows this lane owns (broadcast reads)
            const float* xb = xbb + (tl << 6);
            f32x4 xp[8];
            xp[0] = *(const f32x4*)(xb +  0);
            xp[1] = *(const f32x4*)(xb +  4);
            xp[2] = *(const f32x4*)(xb + 16);
            xp[3] = *(const f32x4*)(xb + 20);
            xp[4] = *(const f32x4*)(xb + 32);
            xp[5] = *(const f32x4*)(xb + 36);
            xp[6] = *(const f32x4*)(xb + 48);
            xp[7] = *(const f32x4*)(xb + 52);
            if (tl != dTl) {
#pragma unroll
                for (int q = 0; q < 16; ++q) {
                    float d2 = fmaf(-2.f, dm[q],
                                    xp[q >> 1][(q & 1) << 1] + y2c);
                    d2 = fmaxf(d2, 0.f);
                    const float t = __builtin_amdgcn_exp2f(
                        fmaf(-LOG2E, __builtin_amdgcn_sqrtf(d2),
                             xp[q >> 1][((q & 1) << 1) + 1]));
                    if ((q & 3) == 0) acc0 += t;
                    else if ((q & 3) == 1) acc1 += t;
                    else if ((q & 3) == 2) acc2 += t;
                    else acc3 += t;
                }
            } else {                                // diagonal tile: strict j>i
#pragma unroll
                for (int q = 0; q < 16; ++q) {
                    float d2 = fmaf(-2.f, dm[q],
                                    xp[q >> 1][(q & 1) << 1] + y2c);
                    d2 = fmaxf(d2, 0.f);
                    float t = __builtin_amdgcn_exp2f(
                        fmaf(-LOG2E, __builtin_amdgcn_sqrtf(d2),
                             xp[q >> 1][((q & 1) << 1) + 1]));
                    const int rq = (q & 3) + ((q >> 2) << 3) + kh4;
                    if (lane31 <= rq) t = 0.f;
                    if ((q & 3) == 0) acc0 += t;
                    else if ((q & 3) == 1) acc1 += t;
                    else if ((q & 3) == 2) acc2 += t;
                    else acc3 += t;
                }
            }
        }
        const float val = (acc0 + acc1 + acc2 + acc3) * Ec;
        const float wsum = waveReduce(val);
        if ((tid & 63) == 0) smred[wid] = wsum;
        __syncthreads();
        if (tid == 0)
            atomicAdd(&ws[isPP ? 0 : 2],
                      smred[0] + smred[1] + smred[2] + smred[3]);
    }

    // ---------------- completion + final reduction ----------------
    __threadfence();
    if (tid == 0) {
        const unsigned old = atomicAdd((unsigned*)(ws + 4), 1u);
        if (old == NB_TOT - 1) {
            const float s0 = atomicAdd(&ws[0], 0.f);   // nonlink_pp
            const float l1 = atomicAdd(&ws[1], 0.f);   // link_pp
            const float s2 = atomicAdd(&ws[2], 0.f);   // nonlink_ap
            const float l3 = atomicAdd(&ws[3], 0.f);   // link_ap
            out[0] = 0.5f * ((s0 - l1) + (s2 - l3)) / (float)N_PP;
        }
    }
}

extern "C" void kernel_launch(void* const* d_in, const int* in_sizes, int n_in,
                              void* d_out, int out_size, void* d_ws, size_t ws_size,
                              hipStream_t stream) {
    const float* p_star   = (const float*)d_in[0];
    const float* p        = (const float*)d_in[1];
    const float* a        = (const float*)d_in[2];
    const float* beta_ap  = (const float*)d_in[3];
    const float* gamma_pp = (const float*)d_in[4];
    const int*   edges_pp = (const int*)d_in[5];
    const int*   edges_ap = (const int*)d_in[6];

    hipMemsetAsync(d_ws, 0, 32, stream);
    hipLaunchKernelGGL(fused_kernel, dim3(NB_TOT), dim3(256), 0, stream,
                       p_star, p, a, beta_ap, gamma_pp, edges_pp, edges_ap,
                       (float*)d_ws, (float*)d_out);
}